// Round 1
// 634.768 us; speedup vs baseline: 1.4730x; 1.4730x over previous
//
#include <hip/hip_runtime.h>

#define IN_F   4096
#define OUT_F  4096
#define BWD    8
#define TAPS   17          // 2*BWD + 1
#define N_TOK  16384
#define TPB    256
#define OPT    4           // outputs per thread (one 16B store)
#define WIN    (OPT + 2*BWD)   // 20-float x window per thread
#define TN     32          // tokens per block

typedef float f4 __attribute__((ext_vector_type(4)));

// launch_bounds(256, 2): VGPR cap 256 (512/2). The per-thread live set is
// ~100 regs (68 band weights + 20-float x window + acc + addressing).
// The previous (256, 4) build allocated only 64 VGPRs -> the 68 weights
// were demoted to per-token reloads (~70 VMEM ops/token/thread) which was
// the real bottleneck (VALUBusy 5%, 1.75 TB/s).
__global__ __launch_bounds__(TPB, 2)
void BandLinear_kernel(const float* __restrict__ x,
                       const float* __restrict__ w,
                       const float* __restrict__ bias,
                       float* __restrict__ out) {
    const int g  = blockIdx.x * TPB + threadIdx.x;  // output-quad index, 0..1023
    const int o0 = g * OPT;                         // first output col, 0..4092
    const int n0 = blockIdx.y * TN;                 // first token of this strip

    // ---- load band weights + bias into registers (once per block strip) ----
    float wreg[OPT][TAPS];
    float breg[OPT];
#pragma unroll
    for (int j = 0; j < OPT; ++j) {
        const int o = o0 + j;
        breg[j] = bias[o];
        const float* wrow = w + (size_t)o * IN_F;
#pragma unroll
        for (int t = 0; t < TAPS; ++t) {
            const int c = o + t - BWD;
            wreg[j][t] = (c >= 0 && c < IN_F) ? wrow[c] : 0.0f;
        }
    }

    const bool edge = (o0 - BWD < 0) || (o0 + OPT - 1 + BWD >= IN_F);

    // ---- stream tokens ----
    for (int tt = 0; tt < TN; ++tt) {
        const int n = n0 + tt;
        const float* xr = x + (size_t)n * IN_F;

        float xv[WIN];
        if (!edge) {
            // window starts at o0-8 -> byte offset 16*g - 32, 16B aligned
            const f4* p = (const f4*)(xr + (o0 - BWD));
#pragma unroll
            for (int k = 0; k < WIN / 4; ++k) {
                f4 v = p[k];
                xv[4 * k + 0] = v.x;
                xv[4 * k + 1] = v.y;
                xv[4 * k + 2] = v.z;
                xv[4 * k + 3] = v.w;
            }
        } else {
            // row-edge quads: clamped scalar loads (their OOB weights are 0)
#pragma unroll
            for (int k = 0; k < WIN; ++k) {
                int c = o0 - BWD + k;
                c = c < 0 ? 0 : (c >= IN_F ? IN_F - 1 : c);
                xv[k] = xr[c];
            }
        }

        float acc[OPT];
#pragma unroll
        for (int j = 0; j < OPT; ++j) {
            float a = breg[j];
#pragma unroll
            for (int t = 0; t < TAPS; ++t)
                a = fmaf(wreg[j][t], xv[j + t], a);
            acc[j] = a;
        }

        f4 res;
        res.x = acc[0]; res.y = acc[1]; res.z = acc[2]; res.w = acc[3];
        __builtin_nontemporal_store(res, (f4*)(out + (size_t)n * OUT_F + o0));
    }
}

extern "C" void kernel_launch(void* const* d_in, const int* in_sizes, int n_in,
                              void* d_out, int out_size, void* d_ws, size_t ws_size,
                              hipStream_t stream) {
    const float* x    = (const float*)d_in[0];
    const float* w    = (const float*)d_in[1];
    const float* bias = (const float*)d_in[2];
    // d_in[3] is the band mask; its structure (|i-j| <= 8) is hardcoded.
    float* out = (float*)d_out;

    dim3 grid(OUT_F / (TPB * OPT), N_TOK / TN);  // (4, 512)
    BandLinear_kernel<<<grid, TPB, 0, stream>>>(x, w, bias, out);
}